// Round 9
// baseline (294.885 us; speedup 1.0000x reference)
//
#include <hip/hip_runtime.h>
#include <math.h>

#define B_  2
#define S_  2048
#define D_  1024
#define H_  16
#define HD_ 64
#define M_  (B_*S_)   // 4096

typedef __attribute__((ext_vector_type(8))) short bf16x8;
typedef __attribute__((ext_vector_type(4))) float f32x4;
typedef unsigned short ushort_t;

#define MFMA32 __builtin_amdgcn_mfma_f32_16x16x32_bf16

__device__ inline unsigned short f2bf(float x) {           // RTN-even
    unsigned u = __float_as_uint(x);
    unsigned r = (u + 0x7fff + ((u >> 16) & 1)) >> 16;
    return (unsigned short)r;
}
__device__ inline void gload16(const ushort_t* g, ushort_t* l) {
    __builtin_amdgcn_global_load_lds(
        (const __attribute__((address_space(1))) unsigned*)g,
        (__attribute__((address_space(3))) unsigned*)l, 16, 0, 0);
}

// ---------------------------------------------------------------------------
// prep: one launch for rope tables + all fp32->bf16 converts.
// ---------------------------------------------------------------------------
__global__ __launch_bounds__(256) void prep(
    const float* __restrict__ qa, const float* __restrict__ ka,
    const float* __restrict__ va,
    const float* __restrict__ qw, const float* __restrict__ kw,
    const float* __restrict__ vw, const float* __restrict__ ow,
    ushort_t* __restrict__ qab, ushort_t* __restrict__ kab,
    ushort_t* __restrict__ vab,
    ushort_t* __restrict__ qwb, ushort_t* __restrict__ kwb,
    ushort_t* __restrict__ vwb, ushort_t* __restrict__ owb,
    float* __restrict__ cost, float* __restrict__ sint)
{
    const int z = blockIdx.y;
    const int i = blockIdx.x * 256 + threadIdx.x;
    if (z == 7) {
        if (blockIdx.x >= (S_ * 32) / 256) return;
        int s = i >> 5, w = i & 31;
        double inv = pow(10000.0, -((double)(2 * w) / (double)HD_));
        double ang = (double)s * inv;
        cost[i] = (float)cos(ang);
        sint[i] = (float)sin(ang);
        return;
    }
    const float* in;
    ushort_t* dst;
    int n4;
    switch (z) {
        case 0: in = qa; dst = qab; n4 = (M_ * D_) / 4; break;
        case 1: in = ka; dst = kab; n4 = (M_ * D_) / 4; break;
        case 2: in = va; dst = vab; n4 = (M_ * D_) / 4; break;
        case 3: in = qw; dst = qwb; n4 = (D_ * D_) / 4; break;
        case 4: in = kw; dst = kwb; n4 = (D_ * D_) / 4; break;
        case 5: in = vw; dst = vwb; n4 = (D_ * D_) / 4; break;
        default: in = ow; dst = owb; n4 = (D_ * D_) / 4; break;
    }
    if (i >= n4) return;
    float4 v = ((const float4*)in)[i];
    unsigned short h0 = f2bf(v.x), h1 = f2bf(v.y), h2 = f2bf(v.z), h3 = f2bf(v.w);
    ((uint2*)dst)[i] = make_uint2((unsigned)h0 | ((unsigned)h1 << 16),
                                  (unsigned)h2 | ((unsigned)h3 << 16));
}

// ---------------------------------------------------------------------------
// Fused QKV projection v2: REGISTER-DIRECT fragments (no LDS, no barriers).
// The staged LDS image was a pure pass-through (af[mt] for lane (l16,quad)
// == A[bm + (wm*4+mt)*16 + l16][k0 + quad*8]); load fragments straight from
// global. Each wave independently owns a 64x64 output quadrant; two named
// fragment sets = distance-2 prefetch; compiler emits the counted waits.
// 64B-line coalesced (quads 0..3 of a row share a line); W reuse via L2
// (XCD swizzle keeps the 8 column-blocks of a panel co-XCD).
// ---------------------------------------------------------------------------
__global__ __launch_bounds__(256, 3) void fused_qkv(
    const ushort_t* __restrict__ A0, const ushort_t* __restrict__ A1,
    const ushort_t* __restrict__ A2,
    const ushort_t* __restrict__ W0, const ushort_t* __restrict__ W1,
    const ushort_t* __restrict__ W2,
    const float* __restrict__ b0, const float* __restrict__ b1,
    const float* __restrict__ b2,
    ushort_t* __restrict__ O0, ushort_t* __restrict__ O1,
    ushort_t* __restrict__ O2,
    const float* __restrict__ cost, const float* __restrict__ sint)
{
    const int tid  = threadIdx.x;
    const int wq   = tid >> 6;
    const int lane = tid & 63;
    const int l16  = lane & 15;
    const int quad = lane >> 4;

    // XCD swizzle: grid (8,32,3), hw-linear = x + 8y + 256z, xcd = flat%8.
    const unsigned flat = blockIdx.x + (blockIdx.y << 3) + (blockIdx.z << 8);
    const unsigned xcd  = flat & 7;
    const unsigned slot = flat >> 3;          // 0..95
    const int z   = (int)(slot >> 5);         // 0..2
    const unsigned rr = slot & 31;
    const int bm  = (int)(xcd * 4 + (rr >> 3)) * 128;
    const int bn  = (int)(rr & 7) * 128;

    const ushort_t* A = z == 0 ? A0 : z == 1 ? A1 : A2;
    const ushort_t* W = z == 0 ? W0 : z == 1 ? W1 : W2;
    const float* bias = z == 0 ? b0 : z == 1 ? b1 : b2;

    const int wm = wq >> 1, wn = wq & 1;

    // per-lane fragment row base addresses (k advances via offset)
    const ushort_t* aAddr[4];
    const ushort_t* wAddr[4];
#pragma unroll
    for (int mt = 0; mt < 4; ++mt)
        aAddr[mt] = A + (size_t)(bm + wm * 64 + mt * 16 + l16) * D_ + quad * 8;
#pragma unroll
    for (int nt = 0; nt < 4; ++nt)
        wAddr[nt] = W + (size_t)(bn + wn * 64 + nt * 16 + l16) * D_ + quad * 8;

    f32x4 acc[4][4];
#pragma unroll
    for (int mt = 0; mt < 4; ++mt)
#pragma unroll
        for (int nt = 0; nt < 4; ++nt)
            acc[mt][nt] = (f32x4){0.f, 0.f, 0.f, 0.f};

    // prologue: k-chunks 0 and 32 into the two fragment sets
    bf16x8 aA[4], wA[4], aB[4], wB[4];
#pragma unroll
    for (int j = 0; j < 4; ++j) {
        aA[j] = *(const bf16x8*)(aAddr[j]);
        wA[j] = *(const bf16x8*)(wAddr[j]);
        aB[j] = *(const bf16x8*)(aAddr[j] + 32);
        wB[j] = *(const bf16x8*)(wAddr[j] + 32);
    }

    for (int k0 = 0; k0 < D_; k0 += 64) {
        // ---- tile k0 (set A) ----
#pragma unroll
        for (int mt = 0; mt < 4; ++mt)
#pragma unroll
            for (int nt = 0; nt < 4; ++nt)
                acc[mt][nt] = MFMA32(aA[mt], wA[nt], acc[mt][nt], 0, 0, 0);
        if (k0 + 64 < D_) {
#pragma unroll
            for (int j = 0; j < 4; ++j) {
                aA[j] = *(const bf16x8*)(aAddr[j] + k0 + 64);
                wA[j] = *(const bf16x8*)(wAddr[j] + k0 + 64);
            }
        }
        // ---- tile k0+32 (set B) ----
#pragma unroll
        for (int mt = 0; mt < 4; ++mt)
#pragma unroll
            for (int nt = 0; nt < 4; ++nt)
                acc[mt][nt] = MFMA32(aB[mt], wB[nt], acc[mt][nt], 0, 0, 0);
        if (k0 + 96 < D_) {
#pragma unroll
            for (int j = 0; j < 4; ++j) {
                aB[j] = *(const bf16x8*)(aAddr[j] + k0 + 96);
                wB[j] = *(const bf16x8*)(wAddr[j] + k0 + 96);
            }
        }
    }

    if (z == 0) {
        const float scale = 0.18033688011112042f;   // hd^-0.5 * log2(e)
#pragma unroll
        for (int mt = 0; mt < 4; ++mt) {
            int m = bm + wm * 64 + mt * 16 + quad * 4;
#pragma unroll
            for (int nt = 0; nt < 4; ++nt) {
                int n = bn + wn * 64 + nt * 16 + l16;
                float bb = bias[n];
                int h = n >> 6, d = n & 63, p = d >> 1;
#pragma unroll
                for (int r = 0; r < 4; ++r) {
                    int mm = m + r;
                    int s = mm & (S_ - 1), b = mm >> 11;
                    float x = acc[mt][nt][r] + bb;
                    float cs = cost[s * 32 + p], sn = sint[s * 32 + p];
                    float part = __shfl_xor(x, 1);
                    float y = (d & 1) ? (part * sn + x * cs)
                                      : (x * cs - part * sn);
                    O0[((size_t)(b * H_ + h) * S_ + s) * HD_ + d] = f2bf(y * scale);
                }
            }
        }
    } else if (z == 1) {
        // K: RoPE then scatter into QK A-fragment image
#pragma unroll
        for (int mt = 0; mt < 4; ++mt) {
            int m = bm + wm * 64 + mt * 16 + quad * 4;
#pragma unroll
            for (int nt = 0; nt < 4; ++nt) {
                int n = bn + wn * 64 + nt * 16 + l16;
                float bb = bias[n];
                int h = n >> 6, d = n & 63, p = d >> 1;
                int sub = ((d >> 5) & 1);
                int dq  = (d >> 3) & 3;
                int dj  = d & 7;
#pragma unroll
                for (int r = 0; r < 4; ++r) {
                    int mm = m + r;
                    int s = mm & (S_ - 1), b = mm >> 11;
                    float x = acc[mt][nt][r] + bb;
                    float cs = cost[s * 32 + p], sn = sint[s * 32 + p];
                    float part = __shfl_xor(x, 1);
                    float y = (d & 1) ? (part * sn + x * cs)
                                      : (x * cs - part * sn);
                    int kt  = s >> 5;
                    int st  = ((s >> 4) & 1) * 2 + sub;
                    size_t idx = ((size_t)(b * H_ + h) * 64 + kt) * 2048
                               + st * 512 + dq * 128 + (s & 15) * 8 + dj;
                    O1[idx] = f2bf(y);
                }
            }
        }
    } else {
        // V: scatter into lane-linear PV B-fragment image, uint2 stores
#pragma unroll
        for (int mt = 0; mt < 4; ++mt) {
            int m = bm + wm * 64 + mt * 16 + quad * 4;
            int b = m >> 11, s0 = m & (S_ - 1);
            int vt = s0 >> 5;
            int kk = s0 & 31;
            int qd = (kk & 15) >> 2;            // key quad
            int w0 = ((kk >> 4) & 1) * 4;       // key 16-group -> j base
#pragma unroll
            for (int nt = 0; nt < 4; ++nt) {
                int n = bn + wn * 64 + nt * 16 + l16;
                float bb = bias[n];
                int h = n >> 6, d = n & 63;
                int mtv = d >> 4, dd = d & 15;
                unsigned short hh[4];
#pragma unroll
                for (int r = 0; r < 4; ++r)
                    hh[r] = f2bf(acc[mt][nt][r] + bb);
                size_t idx = ((size_t)(b * H_ + h) * 64 + vt) * 2048
                           + mtv * 512 + qd * 128 + dd * 8 + w0;
                *(uint2*)(O2 + idx) = make_uint2(
                    (unsigned)hh[0] | ((unsigned)hh[1] << 16),
                    (unsigned)hh[2] | ((unsigned)hh[3] << 16));
            }
        }
    }
}

// ---------------------------------------------------------------------------
// Output projection v2: BM=64, BN=64, 4 waves (2x2), wave tile 32x32.
// Grid (16,64) = 1024 blocks = 4 blocks/CU. 3-buffer distance-2, ONE barrier
// per K-step, counted vmcnt.
// ---------------------------------------------------------------------------
__global__ __launch_bounds__(256, 4) void proj_o(
    const ushort_t* __restrict__ A, const ushort_t* __restrict__ W,
    const float* __restrict__ bias, float* __restrict__ outf)
{
    __shared__ ushort_t Ab[6144];        // 3 buffers x 2048 ushort (4 KB)
    __shared__ ushort_t Wb[6144];

    const int tid  = threadIdx.x;
    const int wq   = tid >> 6;
    const int lane = tid & 63;
    const int l16  = lane & 15;
    const int quad = lane >> 4;

    // XCD swizzle: grid (16,64), flat = x + 16y; xcd = flat&7.
    const unsigned flat = blockIdx.x + (blockIdx.y << 4);
    const unsigned xcd  = flat & 7;
    const unsigned slot = flat >> 3;          // 0..127
    const int bm = (int)(xcd * 8 + (slot >> 4)) * 64;
    const int bn = (int)(slot & 15) * 64;

    const int m16 = tid & 15;
    const int akq = (tid >> 4) & 3;
    const int tw  = tid >> 6;

    const ushort_t* gA = A + (size_t)(bm + tw * 16 + m16) * D_ + akq * 8;
    const ushort_t* gW = W + (size_t)(bn + tw * 16 + m16) * D_ + akq * 8;

    const int wm = wq >> 1, wn = wq & 1;

    f32x4 acc[2][2];
#pragma unroll
    for (int mt = 0; mt < 2; ++mt)
#pragma unroll
        for (int nt = 0; nt < 2; ++nt)
            acc[mt][nt] = (f32x4){0.f, 0.f, 0.f, 0.f};

    // prologue: stage tiles 0 and 1
    gload16(gA,      &Ab[tw * 512]);
    gload16(gW,      &Wb[tw * 512]);
    gload16(gA + 32, &Ab[2048 + tw * 512]);
    gload16(gW + 32, &Wb[2048 + tw * 512]);

    int bcur = 0;
    for (int k = 0; k < 32; ++k) {
        if (k < 31) {
            asm volatile("s_waitcnt vmcnt(2)" ::: "memory");
        } else {
            asm volatile("s_waitcnt vmcnt(0)" ::: "memory");
        }
        __builtin_amdgcn_sched_barrier(0);
        __builtin_amdgcn_s_barrier();
        __builtin_amdgcn_sched_barrier(0);

        if (k < 30) {
            int bnx = bcur + 2; if (bnx >= 3) bnx -= 3;
            int ko = (k + 2) * 32;
            gload16(gA + ko, &Ab[bnx * 2048 + tw * 512]);
            gload16(gW + ko, &Wb[bnx * 2048 + tw * 512]);
        }

        const ushort_t* Abc = &Ab[bcur * 2048];
        const ushort_t* Wbc = &Wb[bcur * 2048];

        bf16x8 af[2], wf[2];
#pragma unroll
        for (int mt = 0; mt < 2; ++mt)
            af[mt] = *(const bf16x8*)&Abc[(wm * 2 + mt) * 512 + lane * 8];
#pragma unroll
        for (int nt = 0; nt < 2; ++nt)
            wf[nt] = *(const bf16x8*)&Wbc[(wn * 2 + nt) * 512 + lane * 8];
#pragma unroll
        for (int mt = 0; mt < 2; ++mt)
#pragma unroll
            for (int nt = 0; nt < 2; ++nt)
                acc[mt][nt] = MFMA32(af[mt], wf[nt], acc[mt][nt], 0, 0, 0);

        bcur += 1; if (bcur >= 3) bcur -= 3;
    }

#pragma unroll
    for (int mt = 0; mt < 2; ++mt) {
        int m = bm + wm * 32 + mt * 16 + quad * 4;
#pragma unroll
        for (int nt = 0; nt < 2; ++nt) {
            int n = bn + wn * 32 + nt * 16 + l16;
            float bb = bias[n];
#pragma unroll
            for (int r = 0; r < 4; ++r)
                outf[(size_t)(m + r) * D_ + n] = acc[mt][nt][r] + bb;
        }
    }
}

// ---------------------------------------------------------------------------
// MFMA flash attention v10 (best measured 57.4us). Register-direct K/V,
// no staging LDS, no barriers in loop; two named reg sets = distance-2
// prefetch; split-K merge via dedicated MRG scratch.
// ---------------------------------------------------------------------------
__device__ __forceinline__ void attn_body(
    bf16x8 (&KR)[4], bf16x8 (&VR)[4], int i,
    const bf16x8 (&qa)[4][2], f32x4 (&oacc)[4][4], f32x4 (&osum)[4],
    const bf16x8& ones8, const ushort_t* kp, const ushort_t* vp)
{
    // ---- scores S^T = K·Q^T (log2 domain) ----
    f32x4 s[4][2];
#pragma unroll
    for (int nh = 0; nh < 4; ++nh)
#pragma unroll
        for (int g = 0; g < 2; ++g)
            s[nh][g] = (f32x4){0.f, 0.f, 0.f, 0.f};
    __builtin_amdgcn_s_setprio(1);
#pragma unroll
    for (int c = 0; c < 2; ++c)
#pragma unroll
        for (int nh = 0; nh < 4; ++nh)
#pragma unroll
            for (int g = 0; g < 2; ++g)
                s[nh][g] = MFMA32(KR[g * 2 + c], qa[nh][c], s[nh][g], 0, 0, 0);
    __builtin_amdgcn_s_setprio(0);

    // ---- p = 2^s; pack full 32-key PV B-fragments (j = g*4 + r) ----
    bf16x8 pb8[4];
#pragma unroll
    for (int nh = 0; nh < 4; ++nh) {
        float p00 = __builtin_exp2f(s[nh][0][0]);
        float p01 = __builtin_exp2f(s[nh][0][1]);
        float p02 = __builtin_exp2f(s[nh][0][2]);
        float p03 = __builtin_exp2f(s[nh][0][3]);
        float p10 = __builtin_exp2f(s[nh][1][0]);
        float p11 = __builtin_exp2f(s[nh][1][1]);
        float p12 = __builtin_exp2f(s[nh][1][2]);
        float p13 = __builtin_exp2f(s[nh][1][3]);
        union { bf16x8 v; unsigned u[4]; } t;
        t.u[0] = __builtin_amdgcn_perm(__float_as_uint(p01),
                                       __float_as_uint(p00), 0x07060302);
        t.u[1] = __builtin_amdgcn_perm(__float_as_uint(p03),
                                       __float_as_uint(p02), 0x07060302);
        t.u[2] = __builtin_amdgcn_perm(__float_as_uint(p11),
                                       __float_as_uint(p10), 0x07060302);
        t.u[3] = __builtin_amdgcn_perm(__float_as_uint(p13),
                                       __float_as_uint(p12), 0x07060302);
        pb8[nh] = t.v;
    }

    // ---- PV: O^T += V^T·P^T ----
    __builtin_amdgcn_s_setprio(1);
#pragma unroll
    for (int mt = 0; mt < 4; ++mt)
#pragma unroll
        for (int nh = 0; nh < 4; ++nh)
            oacc[nh][mt] = MFMA32(VR[mt], pb8[nh], oacc[nh][mt], 0, 0, 0);
#pragma unroll
    for (int nh = 0; nh < 4; ++nh)
        osum[nh] = MFMA32(ones8, pb8[nh], osum[nh], 0, 0, 0);
    __builtin_amdgcn_s_setprio(0);

    // ---- prefetch tile i+2 into this (now dead) reg set ----
    if (i + 2 < 32) {
#pragma unroll
        for (int j = 0; j < 4; ++j) {
            KR[j] = *(const bf16x8*)(kp + (size_t)(i + 2) * 4096 + j * 512);
            VR[j] = *(const bf16x8*)(vp + (size_t)(i + 2) * 4096 + j * 512);
        }
    }
}

__global__ __launch_bounds__(256, 2) void attn_mfma(
    const ushort_t* __restrict__ Q, const ushort_t* __restrict__ Kf,
    const ushort_t* __restrict__ Vf, ushort_t* __restrict__ AO)
{
    __shared__ float MRG[128 * 65];      // dedicated split-K scratch (33.3 KB)
    __shared__ float PSB[128];

    const int tid  = threadIdx.x;
    const int wq   = tid >> 6;
    const int lane = tid & 63;
    const int l16  = lane & 15;
    const int quad = lane >> 4;
    const int qg   = wq & 1;
    const int ks   = wq >> 1;

    // XCD swizzle: grid (16,32), flat = x + 16y; each XCD: 4 bh x 16 q-blocks
    const unsigned flat = blockIdx.x + (blockIdx.y << 4);
    const unsigned xcd  = flat & 7;
    const unsigned slot = flat >> 3;            // 0..63
    const int bh   = (int)(xcd * 4 + (slot >> 4));
    const int q0   = (int)(slot & 15) * 128 + qg * 64;

    // Resident Q fragments (B-operand): 4 nh x 2 dim-chunks
    bf16x8 qa[4][2];
#pragma unroll
    for (int nh = 0; nh < 4; ++nh)
#pragma unroll
        for (int c = 0; c < 2; ++c) {
            int row = q0 + nh * 16 + l16;
            qa[nh][c] = *(const bf16x8*)(Q + ((size_t)bh * S_ + row) * HD_
                                           + c * 32 + quad * 8);
        }
#pragma unroll
    for (int nh = 0; nh < 4; ++nh)
#pragma unroll
        for (int c = 0; c < 2; ++c)
            asm volatile("" : "+v"(qa[nh][c]));

    f32x4 oacc[4][4];
    f32x4 osum[4];
#pragma unroll
    for (int nh = 0; nh < 4; ++nh) {
        osum[nh] = (f32x4){0.f, 0.f, 0.f, 0.f};
#pragma unroll
        for (int mt = 0; mt < 4; ++mt)
            oacc[nh][mt] = (f32x4){0.f, 0.f, 0.f, 0.f};
    }

    const bf16x8 ones8 = {(short)0x3F80, (short)0x3F80, (short)0x3F80,
                          (short)0x3F80, (short)0x3F80, (short)0x3F80,
                          (short)0x3F80, (short)0x3F80};

    // per-lane fragment base pointers (lane-linear images)
    const ushort_t* kp = Kf + (size_t)bh * 131072 + ks * 2048 + lane * 8;
    const ushort_t* vp = Vf + (size_t)bh * 131072 + ks * 2048 + lane * 8;

    // prologue: tiles 0 and 1 into the two reg sets
    bf16x8 kA[4], vA[4], kB[4], vB[4];
#pragma unroll
    for (int j = 0; j < 4; ++j) {
        kA[j] = *(const bf16x8*)(kp + j * 512);
        vA[j] = *(const bf16x8*)(vp + j * 512);
        kB[j] = *(const bf16x8*)(kp + 4096 + j * 512);
        vB[j] = *(const bf16x8*)(vp + 4096 + j * 512);
    }

    for (int i = 0; i < 32; i += 2) {
        attn_body(kA, vA, i,     qa, oacc, osum, ones8, kp, vp);
        attn_body(kB, vB, i + 1, qa, oacc, osum, ones8, kp, vp);
    }

    // ---- split-K merge ----
    if (ks == 1) {
#pragma unroll
        for (int nh = 0; nh < 4; ++nh) {
#pragma unroll
            for (int mt = 0; mt < 4; ++mt)
#pragma unroll
                for (int r = 0; r < 4; ++r)
                    MRG[(qg * 64 + nh * 16 + l16) * 65 + mt * 16 + quad * 4 + r]
                        = oacc[nh][mt][r];
            if (quad == 0)
                PSB[qg * 64 + nh * 16 + l16] = osum[nh][0];
        }
    }
    __syncthreads();
    if (ks == 0) {
        const int b = bh >> 4, h = bh & 15;
#pragma unroll
        for (int nh = 0; nh < 4; ++nh) {
            float pst = osum[nh][0] + PSB[qg * 64 + nh * 16 + l16];
            float inv = 1.0f / pst;
            int q = q0 + nh * 16 + l16;
#pragma unroll
            for (int mt = 0; mt < 4; ++mt) {
                unsigned short hh[4];
#pragma unroll
                for (int r = 0; r < 4; ++r) {
                    float x = oacc[nh][mt][r]
                        + MRG[(qg * 64 + nh * 16 + l16) * 65 + mt * 16 + quad * 4 + r];
                    hh[r] = f2bf(x * inv);
                }
                size_t base = ((size_t)b * S_ + q) * D_ + h * HD_
                            + mt * 16 + quad * 4;
                *(uint2*)(AO + base) = make_uint2(
                    (unsigned)hh[0] | ((unsigned)hh[1] << 16),
                    (unsigned)hh[2] | ((unsigned)hh[3] << 16));
            }
        }
    }
}

// ---------------------------------------------------------------------------
extern "C" void kernel_launch(void* const* d_in, const int* in_sizes, int n_in,
                              void* d_out, int out_size, void* d_ws, size_t ws_size,
                              hipStream_t stream) {
    const float* query = (const float*)d_in[0];
    const float* key   = (const float*)d_in[1];
    const float* value = (const float*)d_in[2];
    const float* q_w   = (const float*)d_in[3];
    const float* q_b   = (const float*)d_in[4];
    const float* k_w   = (const float*)d_in[5];
    const float* k_b   = (const float*)d_in[6];
    const float* v_w   = (const float*)d_in[7];
    const float* v_b   = (const float*)d_in[8];
    const float* o_w   = (const float*)d_in[9];
    const float* o_b   = (const float*)d_in[10];
    float* out = (float*)d_out;

    const size_t NT = (size_t)M_ * D_;
    const size_t WT = (size_t)D_ * D_;
    ushort_t* p = (ushort_t*)d_ws;
    ushort_t* qa_b = p; p += NT;
    ushort_t* ka_b = p; p += NT;
    ushort_t* va_b = p; p += NT;
    ushort_t* wqb  = p; p += WT;
    ushort_t* wkb  = p; p += WT;
    ushort_t* wvb  = p; p += WT;
    ushort_t* wob  = p; p += WT;
    ushort_t* Qb   = p; p += NT;
    ushort_t* Kfr  = p; p += NT;
    ushort_t* Vfr  = p; p += NT;
    ushort_t* AO   = p; p += NT;
    float* cost = (float*)p;
    float* sint = cost + (size_t)S_ * 32;

    dim3 gp((unsigned)(NT / 4 / 256), 8);
    prep<<<gp, 256, 0, stream>>>(query, key, value, q_w, k_w, v_w, o_w,
                                 qa_b, ka_b, va_b, wqb, wkb, wvb, wob,
                                 cost, sint);

    dim3 gq(D_ / 128, M_ / 128, 3);
    fused_qkv<<<gq, 256, 0, stream>>>(
        qa_b, ka_b, va_b, wqb, wkb, wvb,
        q_b, k_b, v_b, Qb, Kfr, Vfr, cost, sint);

    dim3 agrid(S_ / 128, B_ * H_);
    attn_mfma<<<agrid, 256, 0, stream>>>(Qb, Kfr, Vfr, AO);

    dim3 go(D_ / 64, M_ / 64);
    proj_o<<<go, 256, 0, stream>>>(AO, wob, o_b, out);
}

// Round 10
// 245.366 us; speedup vs baseline: 1.2018x; 1.2018x over previous
//
#include <hip/hip_runtime.h>
#include <math.h>

#define B_  2
#define S_  2048
#define D_  1024
#define H_  16
#define HD_ 64
#define M_  (B_*S_)   // 4096

typedef __attribute__((ext_vector_type(8))) short bf16x8;
typedef __attribute__((ext_vector_type(4))) float f32x4;
typedef unsigned short ushort_t;

#define MFMA32 __builtin_amdgcn_mfma_f32_16x16x32_bf16

__device__ inline unsigned short f2bf(float x) {           // RTN-even
    unsigned u = __float_as_uint(x);
    unsigned r = (u + 0x7fff + ((u >> 16) & 1)) >> 16;
    return (unsigned short)r;
}
__device__ inline void gload16(const ushort_t* g, ushort_t* l) {
    __builtin_amdgcn_global_load_lds(
        (const __attribute__((address_space(1))) unsigned*)g,
        (__attribute__((address_space(3))) unsigned*)l, 16, 0, 0);
}

// ---------------------------------------------------------------------------
// prep: one launch for rope tables + all fp32->bf16 converts.
// z==7: double pow for inv (precision matters: phase = s*inv, s up to 2047),
// exact double range-reduction, then fast f32 sincos (was full f64 sin/cos).
// ---------------------------------------------------------------------------
__global__ __launch_bounds__(256) void prep(
    const float* __restrict__ qa, const float* __restrict__ ka,
    const float* __restrict__ va,
    const float* __restrict__ qw, const float* __restrict__ kw,
    const float* __restrict__ vw, const float* __restrict__ ow,
    ushort_t* __restrict__ qab, ushort_t* __restrict__ kab,
    ushort_t* __restrict__ vab,
    ushort_t* __restrict__ qwb, ushort_t* __restrict__ kwb,
    ushort_t* __restrict__ vwb, ushort_t* __restrict__ owb,
    float* __restrict__ cost, float* __restrict__ sint)
{
    const int z = blockIdx.y;
    const int i = blockIdx.x * 256 + threadIdx.x;
    if (z == 7) {
        if (blockIdx.x >= (S_ * 32) / 256) return;
        int s = i >> 5, w = i & 31;
        double inv = pow(10000.0, -((double)(2 * w) / (double)HD_));
        double ang = (double)s * inv;
        double r = ang * 0.15915494309189535;   // /(2*pi)
        r -= floor(r);                          // exact frac in [0,1)
        float th = (float)r * 6.283185307179586f;
        cost[i] = __cosf(th);
        sint[i] = __sinf(th);
        return;
    }
    const float* in;
    ushort_t* dst;
    int n4;
    switch (z) {
        case 0: in = qa; dst = qab; n4 = (M_ * D_) / 4; break;
        case 1: in = ka; dst = kab; n4 = (M_ * D_) / 4; break;
        case 2: in = va; dst = vab; n4 = (M_ * D_) / 4; break;
        case 3: in = qw; dst = qwb; n4 = (D_ * D_) / 4; break;
        case 4: in = kw; dst = kwb; n4 = (D_ * D_) / 4; break;
        case 5: in = vw; dst = vwb; n4 = (D_ * D_) / 4; break;
        default: in = ow; dst = owb; n4 = (D_ * D_) / 4; break;
    }
    if (i >= n4) return;
    float4 v = ((const float4*)in)[i];
    unsigned short h0 = f2bf(v.x), h1 = f2bf(v.y), h2 = f2bf(v.z), h3 = f2bf(v.w);
    ((uint2*)dst)[i] = make_uint2((unsigned)h0 | ((unsigned)h1 << 16),
                                  (unsigned)h2 | ((unsigned)h3 << 16));
}

// ---------------------------------------------------------------------------
// Fused QKV projection, bf16 128x128 tile, BK=32 (round-6 best: ~57.6us).
// 3-buffer prefetch-distance-2 pipeline, ONE barrier per K-step (counted
// vmcnt; steady state keeps 4 loads in flight). XCD-swizzled block mapping.
// ---------------------------------------------------------------------------
__global__ __launch_bounds__(256, 3) void fused_qkv(
    const ushort_t* __restrict__ A0, const ushort_t* __restrict__ A1,
    const ushort_t* __restrict__ A2,
    const ushort_t* __restrict__ W0, const ushort_t* __restrict__ W1,
    const ushort_t* __restrict__ W2,
    const float* __restrict__ b0, const float* __restrict__ b1,
    const float* __restrict__ b2,
    ushort_t* __restrict__ O0, ushort_t* __restrict__ O1,
    ushort_t* __restrict__ O2,
    const float* __restrict__ cost, const float* __restrict__ sint)
{
    __shared__ ushort_t Ab[12288];       // 3 buffers x 4 KB
    __shared__ ushort_t Wb[12288];

    const int tid  = threadIdx.x;
    const int wq   = tid >> 6;
    const int lane = tid & 63;
    const int l16  = lane & 15;
    const int quad = lane >> 4;

    // XCD swizzle: grid (8,32,3), hw-linear = x + 8y + 256z, xcd = flat%8.
    const unsigned flat = blockIdx.x + (blockIdx.y << 3) + (blockIdx.z << 8);
    const unsigned xcd  = flat & 7;
    const unsigned slot = flat >> 3;          // 0..95
    const int z   = (int)(slot >> 5);         // 0..2
    const unsigned rr = slot & 31;
    const int bm  = (int)(xcd * 4 + (rr >> 3)) * 128;
    const int bn  = (int)(rr & 7) * 128;

    const ushort_t* A = z == 0 ? A0 : z == 1 ? A1 : A2;
    const ushort_t* W = z == 0 ? W0 : z == 1 ? W1 : W2;
    const float* bias = z == 0 ? b0 : z == 1 ? b1 : b2;

    const int m16 = tid & 15;
    const int akq = (tid >> 4) & 3;
    const int tw  = tid >> 6;

    const ushort_t* gA0 = A + (size_t)(bm + tw * 16 + m16) * D_ + akq * 8;
    const ushort_t* gA1 = gA0 + (size_t)64 * D_;
    const ushort_t* gW0 = W + (size_t)(bn + tw * 16 + m16) * D_ + akq * 8;
    const ushort_t* gW1 = gW0 + (size_t)64 * D_;

    const int wm = wq >> 1, wn = wq & 1;

    f32x4 acc[4][4];
#pragma unroll
    for (int mt = 0; mt < 4; ++mt)
#pragma unroll
        for (int nt = 0; nt < 4; ++nt)
            acc[mt][nt] = (f32x4){0.f, 0.f, 0.f, 0.f};

    // prologue: stage tiles 0 and 1
    gload16(gA0,      &Ab[tw * 512]);
    gload16(gA1,      &Ab[(tw + 4) * 512]);
    gload16(gW0,      &Wb[tw * 512]);
    gload16(gW1,      &Wb[(tw + 4) * 512]);
    gload16(gA0 + 32, &Ab[4096 + tw * 512]);
    gload16(gA1 + 32, &Ab[4096 + (tw + 4) * 512]);
    gload16(gW0 + 32, &Wb[4096 + tw * 512]);
    gload16(gW1 + 32, &Wb[4096 + (tw + 4) * 512]);

    int bcur = 0;
    for (int k = 0; k < 32; ++k) {
        if (k < 31) {
            asm volatile("s_waitcnt vmcnt(4)" ::: "memory");
        } else {
            asm volatile("s_waitcnt vmcnt(0)" ::: "memory");
        }
        __builtin_amdgcn_sched_barrier(0);
        __builtin_amdgcn_s_barrier();
        __builtin_amdgcn_sched_barrier(0);

        if (k < 30) {
            int bnx = bcur + 2; if (bnx >= 3) bnx -= 3;
            int ko = (k + 2) * 32;
            gload16(gA0 + ko, &Ab[bnx * 4096 + tw * 512]);
            gload16(gA1 + ko, &Ab[bnx * 4096 + (tw + 4) * 512]);
            gload16(gW0 + ko, &Wb[bnx * 4096 + tw * 512]);
            gload16(gW1 + ko, &Wb[bnx * 4096 + (tw + 4) * 512]);
        }

        const ushort_t* Abc = &Ab[bcur * 4096];
        const ushort_t* Wbc = &Wb[bcur * 4096];

        bf16x8 af[4], wf[4];
#pragma unroll
        for (int mt = 0; mt < 4; ++mt)
            af[mt] = *(const bf16x8*)&Abc[(wm * 4 + mt) * 512 + lane * 8];
#pragma unroll
        for (int nt = 0; nt < 4; ++nt)
            wf[nt] = *(const bf16x8*)&Wbc[(wn * 4 + nt) * 512 + lane * 8];
#pragma unroll
        for (int mt = 0; mt < 4; ++mt)
#pragma unroll
            for (int nt = 0; nt < 4; ++nt)
                acc[mt][nt] = MFMA32(af[mt], wf[nt], acc[mt][nt], 0, 0, 0);

        bcur += 1; if (bcur >= 3) bcur -= 3;
    }

    if (z == 0) {
        const float scale = 0.18033688011112042f;   // hd^-0.5 * log2(e)
#pragma unroll
        for (int mt = 0; mt < 4; ++mt) {
            int m = bm + wm * 64 + mt * 16 + quad * 4;
#pragma unroll
            for (int nt = 0; nt < 4; ++nt) {
                int n = bn + wn * 64 + nt * 16 + l16;
                float bb = bias[n];
                int h = n >> 6, d = n & 63, p = d >> 1;
#pragma unroll
                for (int r = 0; r < 4; ++r) {
                    int mm = m + r;
                    int s = mm & (S_ - 1), b = mm >> 11;
                    float x = acc[mt][nt][r] + bb;
                    float cs = cost[s * 32 + p], sn = sint[s * 32 + p];
                    float part = __shfl_xor(x, 1);
                    float y = (d & 1) ? (part * sn + x * cs)
                                      : (x * cs - part * sn);
                    O0[((size_t)(b * H_ + h) * S_ + s) * HD_ + d] = f2bf(y * scale);
                }
            }
        }
    } else if (z == 1) {
        // K: RoPE then scatter into QK A-fragment image
#pragma unroll
        for (int mt = 0; mt < 4; ++mt) {
            int m = bm + wm * 64 + mt * 16 + quad * 4;
#pragma unroll
            for (int nt = 0; nt < 4; ++nt) {
                int n = bn + wn * 64 + nt * 16 + l16;
                float bb = bias[n];
                int h = n >> 6, d = n & 63, p = d >> 1;
                int sub = ((d >> 5) & 1);
                int dq  = (d >> 3) & 3;
                int dj  = d & 7;
#pragma unroll
                for (int r = 0; r < 4; ++r) {
                    int mm = m + r;
                    int s = mm & (S_ - 1), b = mm >> 11;
                    float x = acc[mt][nt][r] + bb;
                    float cs = cost[s * 32 + p], sn = sint[s * 32 + p];
                    float part = __shfl_xor(x, 1);
                    float y = (d & 1) ? (part * sn + x * cs)
                                      : (x * cs - part * sn);
                    int kt  = s >> 5;
                    int st  = ((s >> 4) & 1) * 2 + sub;
                    size_t idx = ((size_t)(b * H_ + h) * 64 + kt) * 2048
                               + st * 512 + dq * 128 + (s & 15) * 8 + dj;
                    O1[idx] = f2bf(y);
                }
            }
        }
    } else {
        // V: scatter into lane-linear PV B-fragment image, uint2 stores
#pragma unroll
        for (int mt = 0; mt < 4; ++mt) {
            int m = bm + wm * 64 + mt * 16 + quad * 4;
            int b = m >> 11, s0 = m & (S_ - 1);
            int vt = s0 >> 5;
            int kk = s0 & 31;
            int qd = (kk & 15) >> 2;            // key quad
            int w0 = ((kk >> 4) & 1) * 4;       // key 16-group -> j base
#pragma unroll
            for (int nt = 0; nt < 4; ++nt) {
                int n = bn + wn * 64 + nt * 16 + l16;
                float bb = bias[n];
                int h = n >> 6, d = n & 63;
                int mtv = d >> 4, dd = d & 15;
                unsigned short hh[4];
#pragma unroll
                for (int r = 0; r < 4; ++r)
                    hh[r] = f2bf(acc[mt][nt][r] + bb);
                size_t idx = ((size_t)(b * H_ + h) * 64 + vt) * 2048
                           + mtv * 512 + qd * 128 + dd * 8 + w0;
                *(uint2*)(O2 + idx) = make_uint2(
                    (unsigned)hh[0] | ((unsigned)hh[1] << 16),
                    (unsigned)hh[2] | ((unsigned)hh[3] << 16));
            }
        }
    }
}

// ---------------------------------------------------------------------------
// Output projection (round-6 v1): BM=64, BN=128, BK=32, 4 waves (2x2).
// 3-buffer distance-2, ONE barrier per K-step, XCD swizzle.
// ---------------------------------------------------------------------------
__global__ __launch_bounds__(256, 2) void proj_o(
    const ushort_t* __restrict__ A, const ushort_t* __restrict__ W,
    const float* __restrict__ bias, float* __restrict__ outf)
{
    __shared__ ushort_t Ab[6144];        // 3 buffers x 2 KB
    __shared__ ushort_t Wb[12288];       // 3 buffers x 4 KB

    const int tid  = threadIdx.x;
    const int wq   = tid >> 6;
    const int lane = tid & 63;
    const int l16  = lane & 15;
    const int quad = lane >> 4;

    // XCD swizzle: grid (8,64), flat = x + 8y; each XCD: 8 row-panels x 8 cols
    const unsigned flat = blockIdx.x + (blockIdx.y << 3);
    const unsigned xcd  = flat & 7;
    const unsigned slot = flat >> 3;          // 0..63
    const int bm = (int)(xcd * 8 + (slot >> 3)) * 64;
    const int bn = (int)(slot & 7) * 128;

    const int m16 = tid & 15;
    const int akq = (tid >> 4) & 3;
    const int tw  = tid >> 6;

    const ushort_t* gA  = A + (size_t)(bm + tw * 16 + m16) * D_ + akq * 8;
    const ushort_t* gW0 = W + (size_t)(bn + tw * 16 + m16) * D_ + akq * 8;
    const ushort_t* gW1 = gW0 + (size_t)64 * D_;

    const int wm = wq >> 1, wn = wq & 1;

    f32x4 acc[2][4];
#pragma unroll
    for (int mt = 0; mt < 2; ++mt)
#pragma unroll
        for (int nt = 0; nt < 4; ++nt)
            acc[mt][nt] = (f32x4){0.f, 0.f, 0.f, 0.f};

    // prologue: stage tiles 0 and 1
    gload16(gA,       &Ab[tw * 512]);
    gload16(gW0,      &Wb[tw * 512]);
    gload16(gW1,      &Wb[(tw + 4) * 512]);
    gload16(gA + 32,  &Ab[2048 + tw * 512]);
    gload16(gW0 + 32, &Wb[4096 + tw * 512]);
    gload16(gW1 + 32, &Wb[4096 + (tw + 4) * 512]);

    int bcur = 0;
    for (int k = 0; k < 32; ++k) {
        if (k < 31) {
            asm volatile("s_waitcnt vmcnt(3)" ::: "memory");
        } else {
            asm volatile("s_waitcnt vmcnt(0)" ::: "memory");
        }
        __builtin_amdgcn_sched_barrier(0);
        __builtin_amdgcn_s_barrier();
        __builtin_amdgcn_sched_barrier(0);

        if (k < 30) {
            int bnx = bcur + 2; if (bnx >= 3) bnx -= 3;
            int ko = (k + 2) * 32;
            gload16(gA  + ko, &Ab[bnx * 2048 + tw * 512]);
            gload16(gW0 + ko, &Wb[bnx * 4096 + tw * 512]);
            gload16(gW1 + ko, &Wb[bnx * 4096 + (tw + 4) * 512]);
        }

        const ushort_t* Abc = &Ab[bcur * 2048];
        const ushort_t* Wbc = &Wb[bcur * 4096];

        bf16x8 af[2], wf[4];
#pragma unroll
        for (int mt = 0; mt < 2; ++mt)
            af[mt] = *(const bf16x8*)&Abc[(wm * 2 + mt) * 512 + lane * 8];
#pragma unroll
        for (int nt = 0; nt < 4; ++nt)
            wf[nt] = *(const bf16x8*)&Wbc[(wn * 4 + nt) * 512 + lane * 8];
#pragma unroll
        for (int mt = 0; mt < 2; ++mt)
#pragma unroll
            for (int nt = 0; nt < 4; ++nt)
                acc[mt][nt] = MFMA32(af[mt], wf[nt], acc[mt][nt], 0, 0, 0);

        bcur += 1; if (bcur >= 3) bcur -= 3;
    }

#pragma unroll
    for (int mt = 0; mt < 2; ++mt) {
        int m = bm + wm * 32 + mt * 16 + quad * 4;
#pragma unroll
        for (int nt = 0; nt < 4; ++nt) {
            int n = bn + wn * 64 + nt * 16 + l16;
            float bb = bias[n];
#pragma unroll
            for (int r = 0; r < 4; ++r)
                outf[(size_t)(m + r) * D_ + n] = acc[mt][nt][r] + bb;
        }
    }
}

// ---------------------------------------------------------------------------
// MFMA flash attention v10 (best measured 57.4us). Register-direct K/V,
// no staging LDS, no barriers in loop; two named reg sets = distance-2
// prefetch; split-K merge via dedicated MRG scratch.
// ---------------------------------------------------------------------------
__device__ __forceinline__ void attn_body(
    bf16x8 (&KR)[4], bf16x8 (&VR)[4], int i,
    const bf16x8 (&qa)[4][2], f32x4 (&oacc)[4][4], f32x4 (&osum)[4],
    const bf16x8& ones8, const ushort_t* kp, const ushort_t* vp)
{
    // ---- scores S^T = K·Q^T (log2 domain) ----
    f32x4 s[4][2];
#pragma unroll
    for (int nh = 0; nh < 4; ++nh)
#pragma unroll
        for (int g = 0; g < 2; ++g)
            s[nh][g] = (f32x4){0.f, 0.f, 0.f, 0.f};
    __builtin_amdgcn_s_setprio(1);
#pragma unroll
    for (int c = 0; c < 2; ++c)
#pragma unroll
        for (int nh = 0; nh < 4; ++nh)
#pragma unroll
            for (int g = 0; g < 2; ++g)
                s[nh][g] = MFMA32(KR[g * 2 + c], qa[nh][c], s[nh][g], 0, 0, 0);
    __builtin_amdgcn_s_setprio(0);

    // ---- p = 2^s; pack full 32-key PV B-fragments (j = g*4 + r) ----
    bf16x8 pb8[4];
#pragma unroll
    for (int nh = 0; nh < 4; ++nh) {
        float p00 = __builtin_exp2f(s[nh][0][0]);
        float p01 = __builtin_exp2f(s[nh][0][1]);
        float p02 = __builtin_exp2f(s[nh][0][2]);
        float p03 = __builtin_exp2f(s[nh][0][3]);
        float p10 = __builtin_exp2f(s[nh][1][0]);
        float p11 = __builtin_exp2f(s[nh][1][1]);
        float p12 = __builtin_exp2f(s[nh][1][2]);
        float p13 = __builtin_exp2f(s[nh][1][3]);
        union { bf16x8 v; unsigned u[4]; } t;
        t.u[0] = __builtin_amdgcn_perm(__float_as_uint(p01),
                                       __float_as_uint(p00), 0x07060302);
        t.u[1] = __builtin_amdgcn_perm(__float_as_uint(p03),
                                       __float_as_uint(p02), 0x07060302);
        t.u[2] = __builtin_amdgcn_perm(__float_as_uint(p11),
                                       __float_as_uint(p10), 0x07060302);
        t.u[3] = __builtin_amdgcn_perm(__float_as_uint(p13),
                                       __float_as_uint(p12), 0x07060302);
        pb8[nh] = t.v;
    }

    // ---- PV: O^T += V^T·P^T ----
    __builtin_amdgcn_s_setprio(1);
#pragma unroll
    for (int mt = 0; mt < 4; ++mt)
#pragma unroll
        for (int nh = 0; nh < 4; ++nh)
            oacc[nh][mt] = MFMA32(VR[mt], pb8[nh], oacc[nh][mt], 0, 0, 0);
#pragma unroll
    for (int nh = 0; nh < 4; ++nh)
        osum[nh] = MFMA32(ones8, pb8[nh], osum[nh], 0, 0, 0);
    __builtin_amdgcn_s_setprio(0);

    // ---- prefetch tile i+2 into this (now dead) reg set ----
    if (i + 2 < 32) {
#pragma unroll
        for (int j = 0; j < 4; ++j) {
            KR[j] = *(const bf16x8*)(kp + (size_t)(i + 2) * 4096 + j * 512);
            VR[j] = *(const bf16x8*)(vp + (size_t)(i + 2) * 4096 + j * 512);
        }
    }
}

__global__ __launch_bounds__(256, 2) void attn_mfma(
    const ushort_t* __restrict__ Q, const ushort_t* __restrict__ Kf,
    const ushort_t* __restrict__ Vf, ushort_t* __restrict__ AO)
{
    __shared__ float MRG[128 * 65];      // dedicated split-K scratch (33.3 KB)
    __shared__ float PSB[128];

    const int tid  = threadIdx.x;
    const int wq   = tid >> 6;
    const int lane = tid & 63;
    const int l16  = lane & 15;
    const int quad = lane >> 4;
    const int qg   = wq & 1;
    const int ks   = wq >> 1;

    // XCD swizzle: grid (16,32), flat = x + 16y; each XCD: 4 bh x 16 q-blocks
    const unsigned flat = blockIdx.x + (blockIdx.y << 4);
    const unsigned xcd  = flat & 7;
    const unsigned slot = flat >> 3;            // 0..63
    const int bh   = (int)(xcd * 4 + (slot >> 4));
    const int q0   = (int)(slot & 15) * 128 + qg * 64;

    // Resident Q fragments (B-operand): 4 nh x 2 dim-chunks
    bf16x8 qa[4][2];
#pragma unroll
    for (int nh = 0; nh < 4; ++nh)
#pragma unroll
        for (int c = 0; c < 2; ++c) {
            int row = q0 + nh * 16 + l16;
            qa[nh][c] = *(const bf16x8*)(Q + ((size_t)bh * S_ + row) * HD_
                                           + c * 32 + quad * 8);
        }
#pragma unroll
    for (int nh = 0; nh < 4; ++nh)
#pragma unroll
        for (int c = 0; c < 2; ++c)
            asm volatile("" : "+v"(qa[nh][c]));

    f32x4 oacc[4][4];
    f32x4 osum[4];
#pragma unroll
    for (int nh = 0; nh < 4; ++nh) {
        osum[nh] = (f32x4){0.f, 0.f, 0.f, 0.f};
#pragma unroll
        for (int mt = 0; mt < 4; ++mt)
            oacc[nh][mt] = (f32x4){0.f, 0.f, 0.f, 0.f};
    }

    const bf16x8 ones8 = {(short)0x3F80, (short)0x3F80, (short)0x3F80,
                          (short)0x3F80, (short)0x3F80, (short)0x3F80,
                          (short)0x3F80, (short)0x3F80};

    // per-lane fragment base pointers (lane-linear images)
    const ushort_t* kp = Kf + (size_t)bh * 131072 + ks * 2048 + lane * 8;
    const ushort_t* vp = Vf + (size_t)bh * 131072 + ks * 2048 + lane * 8;

    // prologue: tiles 0 and 1 into the two reg sets
    bf16x8 kA[4], vA[4], kB[4], vB[4];
#pragma unroll
    for (int j = 0; j < 4; ++j) {
        kA[j] = *(const bf16x8*)(kp + j * 512);
        vA[j] = *(const bf16x8*)(vp + j * 512);
        kB[j] = *(const bf16x8*)(kp + 4096 + j * 512);
        vB[j] = *(const bf16x8*)(vp + 4096 + j * 512);
    }

    for (int i = 0; i < 32; i += 2) {
        attn_body(kA, vA, i,     qa, oacc, osum, ones8, kp, vp);
        attn_body(kB, vB, i + 1, qa, oacc, osum, ones8, kp, vp);
    }

    // ---- split-K merge ----
    if (ks == 1) {
#pragma unroll
        for (int nh = 0; nh < 4; ++nh) {
#pragma unroll
            for (int mt = 0; mt < 4; ++mt)
#pragma unroll
                for (int r = 0; r < 4; ++r)
                    MRG[(qg * 64 + nh * 16 + l16) * 65 + mt * 16 + quad * 4 + r]
                        = oacc[nh][mt][r];
            if (quad == 0)
                PSB[qg * 64 + nh * 16 + l16] = osum[nh][0];
        }
    }
    __syncthreads();
    if (ks == 0) {
        const int b = bh >> 4, h = bh & 15;
#pragma unroll
        for (int nh = 0; nh < 4; ++nh) {
            float pst = osum[nh][0] + PSB[qg * 64 + nh * 16 + l16];
            float inv = 1.0f / pst;
            int q = q0 + nh * 16 + l16;
#pragma unroll
            for (int mt = 0; mt < 4; ++mt) {
                unsigned short hh[4];
#pragma unroll
                for (int r = 0; r < 4; ++r) {
                    float x = oacc[nh][mt][r]
                        + MRG[(qg * 64 + nh * 16 + l16) * 65 + mt * 16 + quad * 4 + r];
                    hh[r] = f2bf(x * inv);
                }
                size_t base = ((size_t)b * S_ + q) * D_ + h * HD_
                            + mt * 16 + quad * 4;
                *(uint2*)(AO + base) = make_uint2(
                    (unsigned)hh[0] | ((unsigned)hh[1] << 16),
                    (unsigned)hh[2] | ((unsigned)hh[3] << 16));
            }
        }
    }
}

// ---------------------------------------------------------------------------
extern "C" void kernel_launch(void* const* d_in, const int* in_sizes, int n_in,
                              void* d_out, int out_size, void* d_ws, size_t ws_size,
                              hipStream_t stream) {
    const float* query = (const float*)d_in[0];
    const float* key   = (const float*)d_in[1];
    const float* value = (const float*)d_in[2];
    const float* q_w   = (const float*)d_in[3];
    const float* q_b   = (const float*)d_in[4];
    const float* k_w   = (const float*)d_in[5];
    const float* k_b   = (const float*)d_in[6];
    const float* v_w   = (const float*)d_in[7];
    const float* v_b   = (const float*)d_in[8];
    const float* o_w   = (const float*)d_in[9];
    const float* o_b   = (const float*)d_in[10];
    float* out = (float*)d_out;

    const size_t NT = (size_t)M_ * D_;
    const size_t WT = (size_t)D_ * D_;
    ushort_t* p = (ushort_t*)d_ws;
    ushort_t* qa_b = p; p += NT;
    ushort_t* ka_b = p; p += NT;
    ushort_t* va_b = p; p += NT;
    ushort_t* wqb  = p; p += WT;
    ushort_t* wkb  = p; p += WT;
    ushort_t* wvb  = p; p += WT;
    ushort_t* wob  = p; p += WT;
    ushort_t* Qb   = p; p += NT;
    ushort_t* Kfr  = p; p += NT;
    ushort_t* Vfr  = p; p += NT;
    ushort_t* AO   = p; p += NT;
    float* cost = (float*)p;
    float* sint = cost + (size_t)S_ * 32;

    dim3 gp((unsigned)(NT / 4 / 256), 8);
    prep<<<gp, 256, 0, stream>>>(query, key, value, q_w, k_w, v_w, o_w,
                                 qa_b, ka_b, va_b, wqb, wkb, wvb, wob,
                                 cost, sint);

    dim3 gq(D_ / 128, M_ / 128, 3);
    fused_qkv<<<gq, 256, 0, stream>>>(
        qa_b, ka_b, va_b, wqb, wkb, wvb,
        q_b, k_b, v_b, Qb, Kfr, Vfr, cost, sint);

    dim3 agrid(S_ / 128, B_ * H_);
    attn_mfma<<<agrid, 256, 0, stream>>>(Qb, Kfr, Vfr, AO);

    dim3 go(D_ / 128, M_ / 64);
    proj_o<<<go, 256, 0, stream>>>(AO, wob, o_b, out);
}